// Round 8
// baseline (55.592 us; speedup 1.0000x reference)
//
#include <hip/hip_runtime.h>

#define B_   2048
#define T1_  31
#define D_   128
#define MB_  8

typedef __attribute__((ext_vector_type(8))) short bf16x8;
typedef __attribute__((ext_vector_type(4))) float f32x4;
typedef __attribute__((ext_vector_type(2))) float f32x2;

__device__ __forceinline__ unsigned cvt_pk_bf16(float lo, float hi) {
    unsigned r;
    asm("v_cvt_pk_bf16_f32 %0, %1, %2" : "=v"(r) : "v"(lo), "v"(hi));
    return r;
}
__device__ __forceinline__ unsigned short f2bf(float f) {
    union { float f; unsigned u; } v; v.f = f;
    unsigned r = v.u + 0x7fffu + ((v.u >> 16) & 1u);
    return (unsigned short)(r >> 16);
}
__device__ __forceinline__ float rcpf_(float x) { return __builtin_amdgcn_rcpf(x); }
__device__ __forceinline__ float sigf(float x)  { return rcpf_(1.0f + __expf(-x)); }
__device__ __forceinline__ float tanhf_(float x) {
    float ax = fabsf(x);
    float t  = 1.0f - 2.0f * rcpf_(__expf(2.0f * ax) + 1.0f);
    return copysignf(t, x);
}

// LDS-only barrier: h-staging (LDS) must be visible across waves, but global
// stores (outE) need NOT retire -> avoid __syncthreads()'s vmcnt(0) drain,
// which otherwise puts HBM store latency on the 31-step serial chain.
#define BAR_LDS() asm volatile("s_waitcnt lgkmcnt(0)\n\ts_barrier" ::: "memory")

// 256 blocks x 512 threads; block owns 8 batches for all 31 steps.
// Wave wv owns gate columns { s*128 + wv*16 + (lane&15) : s=0..3 } -> MFMA acc
// holds i,f,g,o of one (row,col) in-register. A-rows are 2x-replicated
// (arow = l15&7), so C rows 8-15 duplicate 0-7: lanes 32-63 read their OWN
// acc[2],acc[3] for rows rb=2,3/6,7 -> no cross-lane redistribute needed.
__global__ __launch_bounds__(512, 2) void enc_fused(
    const float* __restrict__ in,    // [B][31][128]
    const float* __restrict__ Wih,   // [512][128]
    const float* __restrict__ Whh,   // [512][128]
    const float* __restrict__ bih,   // [512]
    const float* __restrict__ bhh,   // [512]
    const float* __restrict__ aw,    // [287]
    float* __restrict__ outW,        // [B][31][128]
    float* __restrict__ outE)        // [B][31][128]
{
    const int tid  = threadIdx.x;
    const int lane = tid & 63;
    const int wv   = tid >> 6;        // wave 0..7
    const int b0   = blockIdx.x * MB_;
    const int l15  = lane & 15;
    const int lq   = lane >> 4;

    // LDS: exactly 64 KB. Xw = 30 wx slots (bf16 [8][128], XOR-swizzled, 2 KB each);
    // wx[30] recycles slot 0 (written at t==1, after all t=0 reads). Hs = h dbuf.
    __shared__ __align__(16) char Xw[30 * MB_ * 256];   // 61440 B
    __shared__ __align__(16) char Hs[2 * MB_ * 256];    // 4096 B

    // ---------------- weight fragments -> registers (issued early) -------------
    // B[k][n]: lane holds k = kf*32 + lq*8 + j, n = s*128 + wv*16 + l15.
    bf16x8 bw[4][8];
    #pragma unroll
    for (int s = 0; s < 4; ++s) {
        int n = s * 128 + wv * 16 + l15;
        #pragma unroll
        for (int kf = 0; kf < 8; ++kf) {
            int kb = kf * 32 + lq * 8;
            const float* wp = (kf < 4) ? (Wih + n * D_ + kb) : (Whh + n * D_ + (kb - 128));
            float4 fa = *(const float4*)(wp);
            float4 fb = *(const float4*)(wp + 4);
            union { bf16x8 v; unsigned u[4]; } tmp;
            tmp.u[0] = cvt_pk_bf16(fa.x, fa.y);
            tmp.u[1] = cvt_pk_bf16(fa.z, fa.w);
            tmp.u[2] = cvt_pk_bf16(fb.x, fb.y);
            tmp.u[3] = cvt_pk_bf16(fb.z, fb.w);
            bw[s][kf] = tmp.v;
        }
    }
    const int col = wv * 16 + l15;
    const float bs0 = bih[col]           + bhh[col];
    const float bs1 = bih[128 + col]     + bhh[128 + col];
    const float bs2 = bih[256 + col]     + bhh[256 + col];
    const float bs3 = bih[384 + col]     + bhh[384 + col];

    // ---------------- phase A: x_score (input cached in registers) -------------
    const int mg = wv;                 // batch row this wave owns in staging
    const int dh = lane;
    const int d0 = 2 * dh;
    const float* pin = in + (size_t)(b0 + mg) * (T1_ * D_) + d0;

    float2 xc[T1_];                    // 62 VGPRs: this thread's input column-pair
    float xs0 = 0.f, xs1 = 0.f;
    #pragma unroll
    for (int t = 0; t < T1_; ++t) {
        float wt = aw[2 * D_ + t];
        xc[t] = *(const float2*)(pin + t * D_);
        xs0 = fmaf(wt, xc[t].x, xs0);
        xs1 = fmaf(wt, xc[t].y, xs1);
    }
    float* attnS = (float*)Xw;         // [8][128] overlay on slots 0-1 (pre-phase only)
    attnS[mg * 128 + d0]     = xs0;
    attnS[mg * 128 + d0 + 1] = xs1;

    // softmax over own row (wave-synchronous LDS exchange within the wave)
    float v0 = attnS[mg * 128 + lane];
    float v1 = attnS[mg * 128 + lane + 64];
    float mx = fmaxf(v0, v1);
    #pragma unroll
    for (int o = 32; o > 0; o >>= 1) mx = fmaxf(mx, __shfl_xor(mx, o));
    float e0 = __expf(v0 - mx), e1 = __expf(v1 - mx);
    float ss = e0 + e1;
    #pragma unroll
    for (int o = 32; o > 0; o >>= 1) ss += __shfl_xor(ss, o);
    float inv = 1.0f / ss;
    attnS[mg * 128 + lane]      = e0 * inv;
    attnS[mg * 128 + lane + 64] = e1 * inv;
    const float a0 = attnS[mg * 128 + d0];
    const float a1 = attnS[mg * 128 + d0 + 1];
    __syncthreads();                   // attn reads done before wx overwrites overlay

    // ---------------- wx pre-phase: all outW + wx bf16 staging (from regs) -----
    const int wxbyte = (4 * dh) ^ (mg << 4);        // swizzled u32 position in row
    float* outWp = outW + (size_t)(b0 + mg) * (T1_ * D_) + d0;
    unsigned wx30 = 0;
    #pragma unroll
    for (int t = 0; t < T1_; ++t) {
        float w0 = a0 * xc[t].x, w1 = a1 * xc[t].y;
        f32x2 wsv; wsv[0] = w0; wsv[1] = w1;
        __builtin_nontemporal_store(wsv, (f32x2*)(outWp + t * D_));
        unsigned u = cvt_pk_bf16(w0, w1);
        if (t < 30) *(unsigned*)(Xw + t * 2048 + mg * 256 + wxbyte) = u;
        else        wx30 = u;
    }
    ((unsigned*)Hs)[tid]       = 0u;   // h(0) = 0, both buffers
    ((unsigned*)Hs)[tid + 512] = 0u;
    __syncthreads();                   // full barrier once (drains outW stores)

    // ---------------- recurrent loop: one LDS-only barrier per step ------------
    const int arow = l15 & 7;          // A-frag row (rows 8-15 replicate 0-7)
    const int asw  = arow << 4;
    bf16x8 wxfr[4];
    #pragma unroll
    for (int kf = 0; kf < 4; ++kf)
        wxfr[kf] = *(const bf16x8*)(Xw + arow * 256 + ((kf * 64 + lq * 16) ^ asw));

    // lane -> output rows rb, rb+1 (via C-row replication; no shfl needed)
    const int rb = ((lane & 31) >> 4) * 4 + ((lane >> 5) << 1);
    const bool hi32 = (lane >= 32);
    float cs0 = 0.f, cs1 = 0.f;
    float* outE0 = outE + (size_t)(b0 + rb)     * (T1_ * D_) + col;
    float* outE1 = outE + (size_t)(b0 + rb + 1) * (T1_ * D_) + col;

    // wx-part of gates for t=0 (independent of h)
    f32x4 accx[4];
    #pragma unroll
    for (int s = 0; s < 4; ++s) {
        f32x4 a_ = {0.f, 0.f, 0.f, 0.f};
        #pragma unroll
        for (int kf = 0; kf < 4; ++kf)
            a_ = __builtin_amdgcn_mfma_f32_16x16x32_bf16(wxfr[kf], bw[s][kf], a_, 0, 0, 0);
        accx[s] = a_;
    }

    for (int t = 0; t < T1_; ++t) {
        // h fragments for this step (the only post-barrier dependency)
        const char* hp = Hs + (t & 1) * 2048 + arow * 256;
        bf16x8 hfr[4];
        #pragma unroll
        for (int kf = 0; kf < 4; ++kf)
            hfr[kf] = *(const bf16x8*)(hp + ((kf * 64 + lq * 16) ^ asw));

        if (t == 1)   // recycle slot 0 with wx[30]; all t=0 reads completed at barrier(0)
            *(unsigned*)(Xw + mg * 256 + wxbyte) = wx30;

        // gates = accx (precomputed wx part) + h @ Whh^T
        f32x4 acc[4];
        #pragma unroll
        for (int s = 0; s < 4; ++s) {
            f32x4 a_ = accx[s];
            #pragma unroll
            for (int kf = 0; kf < 4; ++kf)
                a_ = __builtin_amdgcn_mfma_f32_16x16x32_bf16(hfr[kf], bw[s][4 + kf], a_, 0, 0, 0);
            acc[s] = a_;
        }

        // prefetch next step's wx fragments early (latency hides under elementwise)
        if (t < 30) {
            int slot = (t + 1 == 30) ? 0 : (t + 1);
            #pragma unroll
            for (int kf = 0; kf < 4; ++kf)
                wxfr[kf] = *(const bf16x8*)(Xw + slot * 2048 + arow * 256 + ((kf * 64 + lq * 16) ^ asw));
        }

        // row select via replication: lanes>=32 hold rows rb,rb+1 in acc[2],acc[3]
        float gq0[4], gq1[4];
        #pragma unroll
        for (int s = 0; s < 4; ++s) {
            gq0[s] = hi32 ? acc[s][2] : acc[s][0];
            gq1[s] = hi32 ? acc[s][3] : acc[s][1];
        }

        float iv, fv, gv, ov, cn, hh;
        iv = gq0[0] + bs0; fv = gq0[1] + bs1; gv = gq0[2] + bs2; ov = gq0[3] + bs3;
        cn = sigf(fv) * cs0 + sigf(iv) * tanhf_(gv); cs0 = cn;
        hh = sigf(ov) * tanhf_(cn);
        __builtin_nontemporal_store(hh, outE0 + t * D_);
        unsigned short hb0 = f2bf(hh);

        iv = gq1[0] + bs0; fv = gq1[1] + bs1; gv = gq1[2] + bs2; ov = gq1[3] + bs3;
        cn = sigf(fv) * cs1 + sigf(iv) * tanhf_(gv); cs1 = cn;
        hh = sigf(ov) * tanhf_(cn);
        __builtin_nontemporal_store(hh, outE1 + t * D_);
        unsigned short hb1 = f2bf(hh);

        if (t < 30) {
            char* hw = Hs + ((t + 1) & 1) * 2048;
            *(unsigned short*)(hw + rb * 256       + ((2 * col) ^ (rb << 4)))       = hb0;
            *(unsigned short*)(hw + (rb + 1) * 256 + ((2 * col) ^ ((rb + 1) << 4))) = hb1;

            // wx-part MFMAs for t+1: independent of h(t+1); fills barrier wait and
            // covers next step's hfr ds_read latency.
            #pragma unroll
            for (int s = 0; s < 4; ++s) {
                f32x4 a_ = {0.f, 0.f, 0.f, 0.f};
                #pragma unroll
                for (int kf = 0; kf < 4; ++kf)
                    a_ = __builtin_amdgcn_mfma_f32_16x16x32_bf16(wxfr[kf], bw[s][kf], a_, 0, 0, 0);
                accx[s] = a_;
            }
        }
        BAR_LDS();   // LDS-only visibility; outE stores stay in flight
    }
}

extern "C" void kernel_launch(void* const* d_in, const int* in_sizes, int n_in,
                              void* d_out, int out_size, void* d_ws, size_t ws_size,
                              hipStream_t stream) {
    const float* in  = (const float*)d_in[0];
    const float* Wih = (const float*)d_in[1];
    const float* Whh = (const float*)d_in[2];
    const float* bih = (const float*)d_in[3];
    const float* bhh = (const float*)d_in[4];
    const float* aw  = (const float*)d_in[5];
    // d_in[6] (attn_b) is mathematically dead: softmax is shift-invariant.

    float* outW = (float*)d_out;
    float* outE = outW + (size_t)B_ * T1_ * D_;

    enc_fused<<<dim3(B_ / MB_), dim3(512), 0, stream>>>(in, Wih, Whh, bih, bhh, aw, outW, outE);
}